// Round 1
// baseline (427.285 us; speedup 1.0000x reference)
//
#include <hip/hip_runtime.h>
#include <hip/hip_bf16.h>

// Problem constants: B=8, C=64, C8=8, H=128, W=128
#define BDIM 8
#define CDIM 64
#define C8DIM 8
#define HDIM 128
#define WDIM 128
#define HW (HDIM * WDIM)   // 16384

// ---------------------------------------------------------------------------
// Kernel 1: fused QKV projection as one 80x128 GEMM over N = B*H*W positions.
// Outputs: q (B,8,H,W), k (B,8,H,W), v (B,64,H,W) into workspace (fp32).
// Row o of the unified weight Wall[80][128]:
//   o in [0,8):  q row  -> Wq[o][c] for c<64, 0 for c>=64   (x channels only)
//   o in [8,16): k row  -> Wk[o-8][c-64] for c>=64, 0 else  (y channels only)
//   o in [16,80): v row -> Wv[o-16][c]                       (x then y)
// Each 256-thread block covers 256 positions; thread = (tg in {0,1}, tp in [0,128)):
// computes 40 outputs (tg half) for 2 positions (tp, tp+128).
// ---------------------------------------------------------------------------
__global__ __launch_bounds__(256) void qkv_kernel(
    const float* __restrict__ x, const float* __restrict__ y,
    const float* __restrict__ Wq, const float* __restrict__ bq,
    const float* __restrict__ Wk, const float* __restrict__ bk,
    const float* __restrict__ Wv, const float* __restrict__ bv,
    float* __restrict__ wsq, float* __restrict__ wsk, float* __restrict__ wsv)
{
    __shared__ float sW[128 * 80];   // [c][o] layout: sW[c*80+o]
    __shared__ float sb[80];

    const int t = threadIdx.x;

    // Stage unified weights into LDS
    for (int i = t; i < 128 * 80; i += 256) {
        int c = i / 80;
        int o = i % 80;
        float val;
        if (o < 8) {
            val = (c < 64) ? Wq[o * 64 + c] : 0.0f;
        } else if (o < 16) {
            val = (c >= 64) ? Wk[(o - 8) * 64 + (c - 64)] : 0.0f;
        } else {
            val = Wv[(o - 16) * 128 + c];
        }
        sW[i] = val;
    }
    if (t < 80) {
        sb[t] = (t < 8) ? bq[t] : (t < 16) ? bk[t - 8] : bv[t - 16];
    }
    __syncthreads();

    const int tg = t >> 7;          // 0 or 1: which 40 outputs
    const int tp = t & 127;
    const int g0 = blockIdx.x * 256 + tp;   // global position index (b*HW + p)
    const int b  = g0 >> 14;
    const int p0 = g0 & 16383;
    const int p1 = p0 + 128;                // same batch (256 | 16384)

    const float* xb = x + (size_t)b * CDIM * HW;
    const float* yb = y + (size_t)b * CDIM * HW;

    float a0[40], a1[40];
    #pragma unroll
    for (int i = 0; i < 40; i++) {
        float bias = sb[tg * 40 + i];
        a0[i] = bias;
        a1[i] = bias;
    }

    // x channels (c' = 0..63)
    for (int c = 0; c < 64; c++) {
        float x0 = xb[c * HW + p0];
        float x1 = xb[c * HW + p1];
        const float* wrow = &sW[c * 80 + tg * 40];
        #pragma unroll
        for (int i = 0; i < 40; i++) {
            float w = wrow[i];
            a0[i] += w * x0;
            a1[i] += w * x1;
        }
    }
    // y channels (c' = 64..127)
    for (int c = 0; c < 64; c++) {
        float y0 = yb[c * HW + p0];
        float y1 = yb[c * HW + p1];
        const float* wrow = &sW[(64 + c) * 80 + tg * 40];
        #pragma unroll
        for (int i = 0; i < 40; i++) {
            float w = wrow[i];
            a0[i] += w * y0;
            a1[i] += w * y1;
        }
    }

    // Store
    #pragma unroll
    for (int i = 0; i < 40; i++) {
        int o = tg * 40 + i;
        float* dst;
        if (o < 8) {
            dst = wsq + ((size_t)(b * 8 + o)) * HW;
        } else if (o < 16) {
            dst = wsk + ((size_t)(b * 8 + (o - 8))) * HW;
        } else {
            dst = wsv + ((size_t)(b * 64 + (o - 16))) * HW;
        }
        dst[p0] = a0[i];
        dst[p1] = a1[i];
    }
}

// ---------------------------------------------------------------------------
// Kernel 2: criss-cross attention + residual.
// Block = (b, row-pair). 256 threads: thread (half in {0,1}, c in [0,128))
// owns position (r = r0+half, c). Online softmax over 256 logits:
//   j in [0,128):  column attention, e = q(r,c).k(j,c), masked j==r
//   j in [0,128):  row attention,    e = q(r,c).k(r,j)
// Pass 2 recomputes logits and accumulates P*V into 64 fp32 registers.
// b = blockIdx.x & 7 pins each batch to one XCD for L2 residency of k[b],v[b].
// ---------------------------------------------------------------------------
__global__ __launch_bounds__(256, 2) void attn_kernel(
    const float* __restrict__ q, const float* __restrict__ k,
    const float* __restrict__ v,
    const float* __restrict__ x, const float* __restrict__ y,
    const float* __restrict__ gptr, float* __restrict__ out)
{
    __shared__ float krow[2][8][128];    // k[b,:,r0+rr,:]
    __shared__ float vrow[2][64][128];   // v[b,:,r0+rr,:]

    const int blk = blockIdx.x;
    const int b  = blk & 7;
    const int rp = blk >> 3;
    const int r0 = rp * 2;
    const int t  = threadIdx.x;

    const float* kb = k + (size_t)b * C8DIM * HW;  // kb[ch*HW + j*128 + c]
    const float* vb = v + (size_t)b * CDIM * HW;

    // Stage the two k rows and two v rows
    for (int i = t; i < 2 * 8 * 128; i += 256) {
        int rr = i >> 10, rem = i & 1023;
        int ch = rem >> 7, cc = rem & 127;
        krow[rr][ch][cc] = kb[ch * HW + (r0 + rr) * 128 + cc];
    }
    for (int i = t; i < 2 * 64 * 128; i += 256) {
        int rr = i >> 13, rem = i & 8191;
        int ch = rem >> 7, cc = rem & 127;
        vrow[rr][ch][cc] = vb[ch * HW + (r0 + rr) * 128 + cc];
    }
    __syncthreads();

    const int half = t >> 7;
    const int c    = t & 127;
    const int rt   = r0 + half;

    float qreg[8];
    #pragma unroll
    for (int ch = 0; ch < 8; ch++)
        qreg[ch] = q[((size_t)(b * 8 + ch)) * HW + rt * 128 + c];

    // ---- Pass 1: online max + sum(exp) over all 256 logits ----
    float m = -1e30f, s = 0.0f;
    for (int j = 0; j < 128; j++) {
        float e = 0.0f;
        #pragma unroll
        for (int ch = 0; ch < 8; ch++)
            e += qreg[ch] * kb[ch * HW + j * 128 + c];
        if (j != rt) {
            float mn = fmaxf(m, e);
            s = s * __expf(m - mn) + __expf(e - mn);
            m = mn;
        }
    }
    for (int j = 0; j < 128; j++) {
        float e = 0.0f;
        #pragma unroll
        for (int ch = 0; ch < 8; ch++)
            e += qreg[ch] * krow[half][ch][j];
        float mn = fmaxf(m, e);
        s = s * __expf(m - mn) + __expf(e - mn);
        m = mn;
    }

    // ---- Pass 2: accumulate exp(e-m) * v ----
    float acc[64];
    #pragma unroll
    for (int ch = 0; ch < 64; ch++) acc[ch] = 0.0f;

    for (int j = 0; j < 128; j++) {
        if (j == rt) continue;   // diagonal mask (uniform branch per wave)
        float e = 0.0f;
        #pragma unroll
        for (int ch = 0; ch < 8; ch++)
            e += qreg[ch] * kb[ch * HW + j * 128 + c];
        float p = __expf(e - m);
        #pragma unroll
        for (int ch = 0; ch < 64; ch++)
            acc[ch] += p * vb[ch * HW + j * 128 + c];
    }
    for (int j = 0; j < 128; j++) {
        float e = 0.0f;
        #pragma unroll
        for (int ch = 0; ch < 8; ch++)
            e += qreg[ch] * krow[half][ch][j];
        float p = __expf(e - m);
        #pragma unroll
        for (int ch = 0; ch < 64; ch++)
            acc[ch] += p * vrow[half][ch][j];
    }

    const float inv   = 1.0f / s;
    const float gamma = gptr[0];
    #pragma unroll
    for (int ch = 0; ch < 64; ch++) {
        size_t idx = ((size_t)(b * 64 + ch)) * HW + rt * 128 + c;
        out[idx] = gamma * acc[ch] * inv + x[idx] + y[idx];
    }
}

// ---------------------------------------------------------------------------
extern "C" void kernel_launch(void* const* d_in, const int* in_sizes, int n_in,
                              void* d_out, int out_size, void* d_ws, size_t ws_size,
                              hipStream_t stream)
{
    const float* x     = (const float*)d_in[0];
    const float* y     = (const float*)d_in[1];
    const float* Wq    = (const float*)d_in[2];
    const float* bq    = (const float*)d_in[3];
    const float* Wk    = (const float*)d_in[4];
    const float* bk    = (const float*)d_in[5];
    const float* Wv    = (const float*)d_in[6];
    const float* bv    = (const float*)d_in[7];
    const float* gamma = (const float*)d_in[8];
    float* out = (float*)d_out;

    // Workspace layout (fp32): q 1M | k 1M | v 8M  = 40 MB total
    float* wsq = (float*)d_ws;
    float* wsk = wsq + (size_t)BDIM * C8DIM * HW;   // +1,048,576
    float* wsv = wsk + (size_t)BDIM * C8DIM * HW;   // +1,048,576 (v: 8,388,608)

    // Kernel 1: 512 blocks x 256 threads (2 positions x 40 outputs per thread)
    qkv_kernel<<<dim3((BDIM * HW) / 256), dim3(256), 0, stream>>>(
        x, y, Wq, bq, Wk, bk, Wv, bv, wsq, wsk, wsv);

    // Kernel 2: 512 blocks (b = blk&7 for XCD affinity, row-pair = blk>>3)
    attn_kernel<<<dim3(BDIM * HDIM / 2), dim3(256), 0, stream>>>(
        wsq, wsk, wsv, x, y, gamma, out);
}

// Round 2
// 397.832 us; speedup vs baseline: 1.0740x; 1.0740x over previous
//
#include <hip/hip_runtime.h>
#include <hip/hip_bf16.h>

// Problem constants: B=8, C=64, C8=8, H=128, W=128
#define BDIM 8
#define CDIM 64
#define C8DIM 8
#define HDIM 128
#define WDIM 128
#define HW (HDIM * WDIM)   // 16384

// ---------------- bf16 helpers (packed in uint) ----------------
__device__ inline unsigned pk_bf16(float a, float b) {
    unsigned ua = (unsigned)__bfloat16_as_ushort(__float2bfloat16(a));
    unsigned ub = (unsigned)__bfloat16_as_ushort(__float2bfloat16(b));
    return ua | (ub << 16);
}
__device__ inline void cvt2(unsigned u, float& lo, float& hi) {
    lo = __uint_as_float(u << 16);
    hi = __uint_as_float(u & 0xffff0000u);
}
__device__ inline uint4 pack8(const float* f) {
    uint4 u;
    u.x = pk_bf16(f[0], f[1]); u.y = pk_bf16(f[2], f[3]);
    u.z = pk_bf16(f[4], f[5]); u.w = pk_bf16(f[6], f[7]);
    return u;
}
__device__ inline float dot8(const float* q, uint4 ku) {
    float lo, hi, e;
    cvt2(ku.x, lo, hi); e  = q[0] * lo + q[1] * hi;
    cvt2(ku.y, lo, hi); e += q[2] * lo + q[3] * hi;
    cvt2(ku.z, lo, hi); e += q[4] * lo + q[5] * hi;
    cvt2(ku.w, lo, hi); e += q[6] * lo + q[7] * hi;
    return e;
}

// ---------------------------------------------------------------------------
// Kernel 1: fused QKV projection (fp32 math), outputs POSITION-MAJOR bf16:
//   q_pm[b][p][0..7], k_pm[b][p][0..7], v_pm[b][p][0..63]   (p = r*128 + c)
// Unified 80x128 weight in LDS; thread = (tg, tp): 40 outputs x 2 positions.
// ---------------------------------------------------------------------------
__global__ __launch_bounds__(256) void qkv_kernel(
    const float* __restrict__ x, const float* __restrict__ y,
    const float* __restrict__ Wq, const float* __restrict__ bq,
    const float* __restrict__ Wk, const float* __restrict__ bk,
    const float* __restrict__ Wv, const float* __restrict__ bv,
    uint4* __restrict__ q_pm, uint4* __restrict__ k_pm, uint4* __restrict__ v_pm)
{
    __shared__ float sW[128 * 80];   // [c][o]
    __shared__ float sb[80];

    const int t = threadIdx.x;

    for (int i = t; i < 128 * 80; i += 256) {
        int c = i / 80;
        int o = i % 80;
        float val;
        if (o < 8) {
            val = (c < 64) ? Wq[o * 64 + c] : 0.0f;
        } else if (o < 16) {
            val = (c >= 64) ? Wk[(o - 8) * 64 + (c - 64)] : 0.0f;
        } else {
            val = Wv[(o - 16) * 128 + c];
        }
        sW[i] = val;
    }
    if (t < 80) {
        sb[t] = (t < 8) ? bq[t] : (t < 16) ? bk[t - 8] : bv[t - 16];
    }
    __syncthreads();

    const int tg = t >> 7;
    const int tp = t & 127;
    const int g0 = blockIdx.x * 256 + tp;
    const int b  = g0 >> 14;
    const int p0 = g0 & 16383;
    const int p1 = p0 + 128;

    const float* xb = x + (size_t)b * CDIM * HW;
    const float* yb = y + (size_t)b * CDIM * HW;

    float a0[40], a1[40];
    #pragma unroll
    for (int i = 0; i < 40; i++) {
        float bias = sb[tg * 40 + i];
        a0[i] = bias;
        a1[i] = bias;
    }

    for (int c = 0; c < 64; c++) {
        float x0 = xb[c * HW + p0];
        float x1 = xb[c * HW + p1];
        const float* wrow = &sW[c * 80 + tg * 40];
        #pragma unroll
        for (int i = 0; i < 40; i++) {
            float w = wrow[i];
            a0[i] += w * x0;
            a1[i] += w * x1;
        }
    }
    for (int c = 0; c < 64; c++) {
        float y0 = yb[c * HW + p0];
        float y1 = yb[c * HW + p1];
        const float* wrow = &sW[(64 + c) * 80 + tg * 40];
        #pragma unroll
        for (int i = 0; i < 40; i++) {
            float w = wrow[i];
            a0[i] += w * y0;
            a1[i] += w * y1;
        }
    }

    const size_t gp0 = (size_t)b * HW + p0;
    const size_t gp1 = (size_t)b * HW + p1;
    if (tg == 0) {
        // q (ch 0..7), k (ch 0..7), v ch 0..23
        q_pm[gp0] = pack8(a0 + 0);
        q_pm[gp1] = pack8(a1 + 0);
        k_pm[gp0] = pack8(a0 + 8);
        k_pm[gp1] = pack8(a1 + 8);
        #pragma unroll
        for (int w = 0; w < 3; w++) {
            v_pm[gp0 * 8 + w] = pack8(a0 + 16 + 8 * w);
            v_pm[gp1 * 8 + w] = pack8(a1 + 16 + 8 * w);
        }
    } else {
        // v ch 24..63
        #pragma unroll
        for (int w = 0; w < 5; w++) {
            v_pm[gp0 * 8 + 3 + w] = pack8(a0 + 8 * w);
            v_pm[gp1 * 8 + 3 + w] = pack8(a1 + 8 * w);
        }
    }
}

// ---------------------------------------------------------------------------
// Kernel 2: criss-cross attention + residual, position-major bf16 q/k/v.
// Block = (b, row-pair). Thread (half, c) owns position (r0+half, c).
// Column branch streams k/v rows from L2 (per-batch set ~2.5 MB, XCD-pinned);
// row branch reads the LDS-staged own-row k/v (broadcast reads).
// ---------------------------------------------------------------------------
__global__ __launch_bounds__(256, 3) void attn_kernel(
    const uint4* __restrict__ kU4,   // per position: 1 uint4 (8 bf16)
    const uint4* __restrict__ qU4,   // per position: 1 uint4 (8 bf16)
    const uint4* __restrict__ vU4,   // per position: 8 uint4 (64 bf16)
    const float* __restrict__ x, const float* __restrict__ y,
    const float* __restrict__ gptr, float* __restrict__ out)
{
    __shared__ uint4 krow[2 * 128];       // [half][j]
    __shared__ uint4 vrow[2 * 128 * 8];   // [half][j][w]

    const int blk = blockIdx.x;
    const int b  = blk & 7;          // batch -> XCD pin (round-robin dispatch)
    const int r0 = (blk >> 3) * 2;
    const int t  = threadIdx.x;

    const size_t base = (size_t)b * HW + (size_t)r0 * 128;   // first staged position

    // Stage 2 rows of k (256 uint4) and v (2048 uint4), fully coalesced
    krow[t] = kU4[base + t];
    #pragma unroll
    for (int i = 0; i < 8; i++)
        vrow[i * 256 + t] = vU4[base * 8 + i * 256 + t];
    __syncthreads();

    const int half = t >> 7;
    const int c    = t & 127;
    const int rt   = r0 + half;

    float qreg[8];
    {
        uint4 qu = qU4[(size_t)b * HW + rt * 128 + c];
        cvt2(qu.x, qreg[0], qreg[1]);
        cvt2(qu.y, qreg[2], qreg[3]);
        cvt2(qu.z, qreg[4], qreg[5]);
        cvt2(qu.w, qreg[6], qreg[7]);
    }

    // ---- Pass 1: online max+sum over 256 logits ----
    float m = -1e30f, s = 0.0f;
    #pragma unroll 4
    for (int j = 0; j < 128; j++) {            // column branch (masked diag)
        uint4 ku = kU4[(size_t)b * HW + j * 128 + c];
        float e = dot8(qreg, ku);
        if (j != rt) {
            float mn = fmaxf(m, e);
            s = s * __expf(m - mn) + __expf(e - mn);
            m = mn;
        }
    }
    #pragma unroll 4
    for (int j = 0; j < 128; j++) {            // row branch (LDS broadcast)
        float e = dot8(qreg, krow[half * 128 + j]);
        float mn = fmaxf(m, e);
        s = s * __expf(m - mn) + __expf(e - mn);
        m = mn;
    }

    // ---- Pass 2: accumulate p * v ----
    float acc[64];
    #pragma unroll
    for (int ch = 0; ch < 64; ch++) acc[ch] = 0.0f;

    #pragma unroll 2
    for (int j = 0; j < 128; j++) {            // column branch
        if (j == rt) continue;
        uint4 ku = kU4[(size_t)b * HW + j * 128 + c];
        float e = dot8(qreg, ku);
        float p = __expf(e - m);
        const uint4* vp = &vU4[((size_t)b * HW + j * 128 + c) * 8];
        #pragma unroll
        for (int w = 0; w < 8; w++) {
            uint4 vu = vp[w];
            float f0, f1;
            cvt2(vu.x, f0, f1); acc[w * 8 + 0] += p * f0; acc[w * 8 + 1] += p * f1;
            cvt2(vu.y, f0, f1); acc[w * 8 + 2] += p * f0; acc[w * 8 + 3] += p * f1;
            cvt2(vu.z, f0, f1); acc[w * 8 + 4] += p * f0; acc[w * 8 + 5] += p * f1;
            cvt2(vu.w, f0, f1); acc[w * 8 + 6] += p * f0; acc[w * 8 + 7] += p * f1;
        }
    }
    #pragma unroll 2
    for (int j = 0; j < 128; j++) {            // row branch (LDS broadcast)
        float e = dot8(qreg, krow[half * 128 + j]);
        float p = __expf(e - m);
        const uint4* vp = &vrow[half * 1024 + j * 8];
        #pragma unroll
        for (int w = 0; w < 8; w++) {
            uint4 vu = vp[w];
            float f0, f1;
            cvt2(vu.x, f0, f1); acc[w * 8 + 0] += p * f0; acc[w * 8 + 1] += p * f1;
            cvt2(vu.y, f0, f1); acc[w * 8 + 2] += p * f0; acc[w * 8 + 3] += p * f1;
            cvt2(vu.z, f0, f1); acc[w * 8 + 4] += p * f0; acc[w * 8 + 5] += p * f1;
            cvt2(vu.w, f0, f1); acc[w * 8 + 6] += p * f0; acc[w * 8 + 7] += p * f1;
        }
    }

    const float inv   = 1.0f / s;
    const float gamma = gptr[0];
    #pragma unroll
    for (int ch = 0; ch < 64; ch++) {
        size_t idx = ((size_t)(b * 64 + ch)) * HW + (size_t)rt * 128 + c;
        out[idx] = gamma * acc[ch] * inv + x[idx] + y[idx];
    }
}

// ---------------------------------------------------------------------------
extern "C" void kernel_launch(void* const* d_in, const int* in_sizes, int n_in,
                              void* d_out, int out_size, void* d_ws, size_t ws_size,
                              hipStream_t stream)
{
    const float* x     = (const float*)d_in[0];
    const float* y     = (const float*)d_in[1];
    const float* Wq    = (const float*)d_in[2];
    const float* bq    = (const float*)d_in[3];
    const float* Wk    = (const float*)d_in[4];
    const float* bk    = (const float*)d_in[5];
    const float* Wv    = (const float*)d_in[6];
    const float* bv    = (const float*)d_in[7];
    const float* gamma = (const float*)d_in[8];
    float* out = (float*)d_out;

    // Workspace (bf16, position-major): q 2MB | k 2MB | v 16MB = 20 MB
    __hip_bfloat16* q_pm = (__hip_bfloat16*)d_ws;
    __hip_bfloat16* k_pm = q_pm + (size_t)BDIM * HW * 8;
    __hip_bfloat16* v_pm = k_pm + (size_t)BDIM * HW * 8;

    qkv_kernel<<<dim3((BDIM * HW) / 256), dim3(256), 0, stream>>>(
        x, y, Wq, bq, Wk, bk, Wv, bv,
        (uint4*)q_pm, (uint4*)k_pm, (uint4*)v_pm);

    attn_kernel<<<dim3(BDIM * HDIM / 2), dim3(256), 0, stream>>>(
        (const uint4*)k_pm, (const uint4*)q_pm, (const uint4*)v_pm,
        x, y, gamma, out);
}

// Round 4
// 130.611 us; speedup vs baseline: 3.2714x; 3.0459x over previous
//
#include <hip/hip_runtime.h>
#include <hip/hip_bf16.h>

// Problem constants: B=8, C=64, C8=8, H=128, W=128
#define BDIM 8
#define CDIM 64
#define C8DIM 8
#define HDIM 128
#define WDIM 128
#define HW (HDIM * WDIM)   // 16384

typedef short bf16x8 __attribute__((ext_vector_type(8)));
typedef float f32x4 __attribute__((ext_vector_type(4)));

// ---------------- bf16 helpers ----------------
__device__ inline unsigned pk_bf16(float a, float b) {
    unsigned ua = (unsigned)__bfloat16_as_ushort(__float2bfloat16(a));
    unsigned ub = (unsigned)__bfloat16_as_ushort(__float2bfloat16(b));
    return ua | (ub << 16);
}
__device__ inline float bf2f(ushort u) { return __uint_as_float(((unsigned)u) << 16); }

// ---------------------------------------------------------------------------
// Kernel 1: fused QKV projection (fp32 math), outputs POSITION-MAJOR bf16:
//   q_pm[b][p] (uint4 = 8 bf16), k_pm[b][p], v_pm[b][p][w:0..7] (w-th uint4 =
//   channels 8w..8w+7).  p = r*128 + c.
// ---------------------------------------------------------------------------
__global__ __launch_bounds__(256) void qkv_kernel(
    const float* __restrict__ x, const float* __restrict__ y,
    const float* __restrict__ Wq, const float* __restrict__ bq,
    const float* __restrict__ Wk, const float* __restrict__ bk,
    const float* __restrict__ Wv, const float* __restrict__ bv,
    uint4* __restrict__ q_pm, uint4* __restrict__ k_pm, uint4* __restrict__ v_pm)
{
    __shared__ float sW[128 * 80];   // [c][o]
    __shared__ float sb[80];

    const int t = threadIdx.x;

    for (int i = t; i < 128 * 80; i += 256) {
        int c = i / 80;
        int o = i % 80;
        float val;
        if (o < 8) {
            val = (c < 64) ? Wq[o * 64 + c] : 0.0f;
        } else if (o < 16) {
            val = (c >= 64) ? Wk[(o - 8) * 64 + (c - 64)] : 0.0f;
        } else {
            val = Wv[(o - 16) * 128 + c];
        }
        sW[i] = val;
    }
    if (t < 80) {
        sb[t] = (t < 8) ? bq[t] : (t < 16) ? bk[t - 8] : bv[t - 16];
    }
    __syncthreads();

    const int tg = t >> 7;
    const int tp = t & 127;
    const int g0 = blockIdx.x * 256 + tp;
    const int b  = g0 >> 14;
    const int p0 = g0 & 16383;
    const int p1 = p0 + 128;

    const float* xb = x + (size_t)b * CDIM * HW;
    const float* yb = y + (size_t)b * CDIM * HW;

    float a0[40], a1[40];
    #pragma unroll
    for (int i = 0; i < 40; i++) {
        float bias = sb[tg * 40 + i];
        a0[i] = bias;
        a1[i] = bias;
    }

    for (int c = 0; c < 64; c++) {
        float x0 = xb[c * HW + p0];
        float x1 = xb[c * HW + p1];
        const float* wrow = &sW[c * 80 + tg * 40];
        #pragma unroll
        for (int i = 0; i < 40; i++) {
            float w = wrow[i];
            a0[i] += w * x0;
            a1[i] += w * x1;
        }
    }
    for (int c = 0; c < 64; c++) {
        float y0 = yb[c * HW + p0];
        float y1 = yb[c * HW + p1];
        const float* wrow = &sW[(64 + c) * 80 + tg * 40];
        #pragma unroll
        for (int i = 0; i < 40; i++) {
            float w = wrow[i];
            a0[i] += w * y0;
            a1[i] += w * y1;
        }
    }

    const size_t gp0 = (size_t)b * HW + p0;
    const size_t gp1 = (size_t)b * HW + p1;
    if (tg == 0) {
        uint4 u;
        u.x = pk_bf16(a0[0], a0[1]); u.y = pk_bf16(a0[2], a0[3]);
        u.z = pk_bf16(a0[4], a0[5]); u.w = pk_bf16(a0[6], a0[7]);
        q_pm[gp0] = u;
        u.x = pk_bf16(a1[0], a1[1]); u.y = pk_bf16(a1[2], a1[3]);
        u.z = pk_bf16(a1[4], a1[5]); u.w = pk_bf16(a1[6], a1[7]);
        q_pm[gp1] = u;
        u.x = pk_bf16(a0[8], a0[9]); u.y = pk_bf16(a0[10], a0[11]);
        u.z = pk_bf16(a0[12], a0[13]); u.w = pk_bf16(a0[14], a0[15]);
        k_pm[gp0] = u;
        u.x = pk_bf16(a1[8], a1[9]); u.y = pk_bf16(a1[10], a1[11]);
        u.z = pk_bf16(a1[12], a1[13]); u.w = pk_bf16(a1[14], a1[15]);
        k_pm[gp1] = u;
        #pragma unroll
        for (int w = 0; w < 3; w++) {
            uint4 v0, v1;
            v0.x = pk_bf16(a0[16 + 8*w + 0], a0[16 + 8*w + 1]);
            v0.y = pk_bf16(a0[16 + 8*w + 2], a0[16 + 8*w + 3]);
            v0.z = pk_bf16(a0[16 + 8*w + 4], a0[16 + 8*w + 5]);
            v0.w = pk_bf16(a0[16 + 8*w + 6], a0[16 + 8*w + 7]);
            v1.x = pk_bf16(a1[16 + 8*w + 0], a1[16 + 8*w + 1]);
            v1.y = pk_bf16(a1[16 + 8*w + 2], a1[16 + 8*w + 3]);
            v1.z = pk_bf16(a1[16 + 8*w + 4], a1[16 + 8*w + 5]);
            v1.w = pk_bf16(a1[16 + 8*w + 6], a1[16 + 8*w + 7]);
            v_pm[gp0 * 8 + w] = v0;
            v_pm[gp1 * 8 + w] = v1;
        }
    } else {
        #pragma unroll
        for (int w = 0; w < 5; w++) {
            uint4 v0, v1;
            v0.x = pk_bf16(a0[8*w + 0], a0[8*w + 1]);
            v0.y = pk_bf16(a0[8*w + 2], a0[8*w + 3]);
            v0.z = pk_bf16(a0[8*w + 4], a0[8*w + 5]);
            v0.w = pk_bf16(a0[8*w + 6], a0[8*w + 7]);
            v1.x = pk_bf16(a1[8*w + 0], a1[8*w + 1]);
            v1.y = pk_bf16(a1[8*w + 2], a1[8*w + 3]);
            v1.z = pk_bf16(a1[8*w + 4], a1[8*w + 5]);
            v1.w = pk_bf16(a1[8*w + 6], a1[8*w + 7]);
            v_pm[gp0 * 8 + 3 + w] = v0;
            v_pm[gp1 * 8 + 3 + w] = v1;
        }
    }
}

// ---------------------------------------------------------------------------
// Kernel 2 (column branch): one block per (b, c).  MFMA tile-GEMMs:
//   QK^T (swapped): D[j][i] = sum_ch K[j][ch] * Q[ch][i]   (K-dim = 8, padded)
//   per-row (i) softmax with diag mask (j == i -> -inf), unnormalized
//   PV: D2[ch][i] = sum_j V[ch][j] * P[j][i]
// Writes: H_t[b][c][ch][i] bf16 (unnormalized), mH[b][c][i], sH[b][c][i] f32.
// A/B fragments use the same (group,elem)->k convention for both operands, so
// correctness is independent of the HW's internal k permutation. C/D layout:
// col = lane&15, row = (lane>>4)*4 + reg (HW-verified).
// ---------------------------------------------------------------------------
__global__ __launch_bounds__(256, 2) void colattn_kernel(
    const uint4* __restrict__ q_pm, const uint4* __restrict__ k_pm,
    const uint4* __restrict__ v_pm,
    ushort* __restrict__ H_t, float* __restrict__ mH_g, float* __restrict__ sH_g)
{
    __shared__ ushort Q_lds[128 * 8];     // [i][ch]
    __shared__ ushort K_lds[128 * 8];     // [j][ch]
    __shared__ ushort V_lds[64 * 136];    // [ch][j], pad 8
    __shared__ ushort P_lds[128 * 136];   // [i][j], pad 8

    const int blk = blockIdx.x;
    const int b  = blk & 7;
    const int cc = blk >> 3;
    const int t  = threadIdx.x;

    if (t < 128) {
        *(uint4*)&Q_lds[t * 8] = q_pm[(size_t)b * HW + (size_t)t * 128 + cc];
    } else {
        int j = t - 128;
        *(uint4*)&K_lds[j * 8] = k_pm[(size_t)b * HW + (size_t)j * 128 + cc];
    }
    {
        int j = t & 127, h = t >> 7;
        const uint4* vp = v_pm + ((size_t)b * HW + (size_t)j * 128 + cc) * 8 + 4 * h;
        #pragma unroll
        for (int qd = 0; qd < 4; qd++) {
            uint4 vu = vp[qd];
            int ch0 = 32 * h + 8 * qd;
            V_lds[(ch0 + 0) * 136 + j] = (ushort)(vu.x & 0xffff);
            V_lds[(ch0 + 1) * 136 + j] = (ushort)(vu.x >> 16);
            V_lds[(ch0 + 2) * 136 + j] = (ushort)(vu.y & 0xffff);
            V_lds[(ch0 + 3) * 136 + j] = (ushort)(vu.y >> 16);
            V_lds[(ch0 + 4) * 136 + j] = (ushort)(vu.z & 0xffff);
            V_lds[(ch0 + 5) * 136 + j] = (ushort)(vu.z >> 16);
            V_lds[(ch0 + 6) * 136 + j] = (ushort)(vu.w & 0xffff);
            V_lds[(ch0 + 7) * 136 + j] = (ushort)(vu.w >> 16);
        }
    }
    __syncthreads();

    const int wv = t >> 6, ln = t & 63, lg = ln >> 4, li = ln & 15;
    const bf16x8 zf = {0, 0, 0, 0, 0, 0, 0, 0};

    // ---- QK^T ----
    bf16x8 afr[8], bfr[2];
    #pragma unroll
    for (int jt = 0; jt < 8; jt++)
        afr[jt] = (lg == 0) ? *(const bf16x8*)&K_lds[(jt * 16 + li) * 8] : zf;
    #pragma unroll
    for (int it2 = 0; it2 < 2; it2++)
        bfr[it2] = (lg == 0) ? *(const bf16x8*)&Q_lds[((2 * wv + it2) * 16 + li) * 8] : zf;

    f32x4 dfr[2][8];
    #pragma unroll
    for (int a = 0; a < 2; a++)
        #pragma unroll
        for (int jt = 0; jt < 8; jt++) dfr[a][jt] = (f32x4){0.f, 0.f, 0.f, 0.f};

    #pragma unroll
    for (int it2 = 0; it2 < 2; it2++)
        #pragma unroll
        for (int jt = 0; jt < 8; jt++)
            dfr[it2][jt] = __builtin_amdgcn_mfma_f32_16x16x32_bf16(
                afr[jt], bfr[it2], dfr[it2][jt], 0, 0, 0);

    // ---- softmax (unnormalized, diag masked) ----
    #pragma unroll
    for (int it2 = 0; it2 < 2; it2++) {
        const int i = (2 * wv + it2) * 16 + li;
        float m = -1e30f;
        #pragma unroll
        for (int jt = 0; jt < 8; jt++)
            #pragma unroll
            for (int rr = 0; rr < 4; rr++) {
                int j = jt * 16 + lg * 4 + rr;
                float e = dfr[it2][jt][rr];
                if (j == i) e = -1e30f;
                dfr[it2][jt][rr] = e;
                m = fmaxf(m, e);
            }
        m = fmaxf(m, __shfl_xor(m, 16));
        m = fmaxf(m, __shfl_xor(m, 32));
        float s = 0.f;
        #pragma unroll
        for (int jt = 0; jt < 8; jt++)
            #pragma unroll
            for (int rr = 0; rr < 4; rr++) {
                float p = __expf(dfr[it2][jt][rr] - m);
                dfr[it2][jt][rr] = p;
                s += p;
            }
        s += __shfl_xor(s, 16);
        s += __shfl_xor(s, 32);
        #pragma unroll
        for (int jt = 0; jt < 8; jt++) {
            uint2 w;
            w.x = pk_bf16(dfr[it2][jt][0], dfr[it2][jt][1]);
            w.y = pk_bf16(dfr[it2][jt][2], dfr[it2][jt][3]);
            *(uint2*)&P_lds[(size_t)i * 136 + jt * 16 + lg * 4] = w;
        }
        if (lg == 0) {
            mH_g[((size_t)b * 128 + cc) * 128 + i] = m;
            sH_g[((size_t)b * 128 + cc) * 128 + i] = s;
        }
    }
    __syncthreads();

    // ---- PV ----
    f32x4 ofr[8];
    #pragma unroll
    for (int itl = 0; itl < 8; itl++) ofr[itl] = (f32x4){0.f, 0.f, 0.f, 0.f};

    #pragma unroll
    for (int ks = 0; ks < 4; ks++) {
        const int jb = ks * 32 + lg * 8;
        bf16x8 av = *(const bf16x8*)&V_lds[(wv * 16 + li) * 136 + jb];
        #pragma unroll
        for (int itl = 0; itl < 8; itl++) {
            bf16x8 bp = *(const bf16x8*)&P_lds[(itl * 16 + li) * 136 + jb];
            ofr[itl] = __builtin_amdgcn_mfma_f32_16x16x32_bf16(av, bp, ofr[itl], 0, 0, 0);
        }
    }

    #pragma unroll
    for (int itl = 0; itl < 8; itl++) {
        const int i = itl * 16 + li;
        #pragma unroll
        for (int rr = 0; rr < 4; rr++) {
            const int ch = wv * 16 + lg * 4 + rr;
            H_t[(((size_t)b * 128 + cc) * 64 + ch) * 128 + i] =
                __bfloat16_as_ushort(__float2bfloat16(ofr[itl][rr]));
        }
    }
}

// ---------------------------------------------------------------------------
// Kernel 3 (row branch + merge): one block per (b, r).  Same GEMM structure
// (no diag mask); epilogue merges with the column branch (mH/sH/H_t) and adds
// the residual:  out = gamma*(H*wH + W*wW)/(sH*wH + sW*wW) + x + y.
// ---------------------------------------------------------------------------
__global__ __launch_bounds__(256, 2) void rowattn_kernel(
    const uint4* __restrict__ q_pm, const uint4* __restrict__ k_pm,
    const uint4* __restrict__ v_pm,
    const ushort* __restrict__ H_t, const float* __restrict__ mH_g,
    const float* __restrict__ sH_g,
    const float* __restrict__ x, const float* __restrict__ y,
    const float* __restrict__ gptr, float* __restrict__ out)
{
    __shared__ ushort Q_lds[128 * 8];     // [i][ch]  (i = column index)
    __shared__ ushort K_lds[128 * 8];     // [j][ch]
    __shared__ ushort V_lds[64 * 136];    // [ch][j]
    __shared__ ushort P_lds[128 * 136];   // [i][j]
    __shared__ float mW_s[128], sW_s[128];

    const int blk = blockIdx.x;
    const int b = blk & 7;
    const int r = blk >> 3;
    const int t = threadIdx.x;

    if (t < 128) {
        *(uint4*)&Q_lds[t * 8] = q_pm[(size_t)b * HW + (size_t)r * 128 + t];
    } else {
        int j = t - 128;
        *(uint4*)&K_lds[j * 8] = k_pm[(size_t)b * HW + (size_t)r * 128 + j];
    }
    {
        int j = t & 127, h = t >> 7;
        const uint4* vp = v_pm + ((size_t)b * HW + (size_t)r * 128 + j) * 8 + 4 * h;
        #pragma unroll
        for (int qd = 0; qd < 4; qd++) {
            uint4 vu = vp[qd];
            int ch0 = 32 * h + 8 * qd;
            V_lds[(ch0 + 0) * 136 + j] = (ushort)(vu.x & 0xffff);
            V_lds[(ch0 + 1) * 136 + j] = (ushort)(vu.x >> 16);
            V_lds[(ch0 + 2) * 136 + j] = (ushort)(vu.y & 0xffff);
            V_lds[(ch0 + 3) * 136 + j] = (ushort)(vu.y >> 16);
            V_lds[(ch0 + 4) * 136 + j] = (ushort)(vu.z & 0xffff);
            V_lds[(ch0 + 5) * 136 + j] = (ushort)(vu.z >> 16);
            V_lds[(ch0 + 6) * 136 + j] = (ushort)(vu.w & 0xffff);
            V_lds[(ch0 + 7) * 136 + j] = (ushort)(vu.w >> 16);
        }
    }
    __syncthreads();

    const int wv = t >> 6, ln = t & 63, lg = ln >> 4, li = ln & 15;
    const bf16x8 zf = {0, 0, 0, 0, 0, 0, 0, 0};

    bf16x8 afr[8], bfr[2];
    #pragma unroll
    for (int jt = 0; jt < 8; jt++)
        afr[jt] = (lg == 0) ? *(const bf16x8*)&K_lds[(jt * 16 + li) * 8] : zf;
    #pragma unroll
    for (int it2 = 0; it2 < 2; it2++)
        bfr[it2] = (lg == 0) ? *(const bf16x8*)&Q_lds[((2 * wv + it2) * 16 + li) * 8] : zf;

    f32x4 dfr[2][8];
    #pragma unroll
    for (int a = 0; a < 2; a++)
        #pragma unroll
        for (int jt = 0; jt < 8; jt++) dfr[a][jt] = (f32x4){0.f, 0.f, 0.f, 0.f};

    #pragma unroll
    for (int it2 = 0; it2 < 2; it2++)
        #pragma unroll
        for (int jt = 0; jt < 8; jt++)
            dfr[it2][jt] = __builtin_amdgcn_mfma_f32_16x16x32_bf16(
                afr[jt], bfr[it2], dfr[it2][jt], 0, 0, 0);

    #pragma unroll
    for (int it2 = 0; it2 < 2; it2++) {
        const int i = (2 * wv + it2) * 16 + li;
        float m = -1e30f;
        #pragma unroll
        for (int jt = 0; jt < 8; jt++)
            #pragma unroll
            for (int rr = 0; rr < 4; rr++)
                m = fmaxf(m, dfr[it2][jt][rr]);
        m = fmaxf(m, __shfl_xor(m, 16));
        m = fmaxf(m, __shfl_xor(m, 32));
        float s = 0.f;
        #pragma unroll
        for (int jt = 0; jt < 8; jt++)
            #pragma unroll
            for (int rr = 0; rr < 4; rr++) {
                float p = __expf(dfr[it2][jt][rr] - m);
                dfr[it2][jt][rr] = p;
                s += p;
            }
        s += __shfl_xor(s, 16);
        s += __shfl_xor(s, 32);
        #pragma unroll
        for (int jt = 0; jt < 8; jt++) {
            uint2 w;
            w.x = pk_bf16(dfr[it2][jt][0], dfr[it2][jt][1]);
            w.y = pk_bf16(dfr[it2][jt][2], dfr[it2][jt][3]);
            *(uint2*)&P_lds[(size_t)i * 136 + jt * 16 + lg * 4] = w;
        }
        if (lg == 0) {
            mW_s[i] = m;
            sW_s[i] = s;
        }
    }
    __syncthreads();

    f32x4 ofr[8];
    #pragma unroll
    for (int itl = 0; itl < 8; itl++) ofr[itl] = (f32x4){0.f, 0.f, 0.f, 0.f};

    #pragma unroll
    for (int ks = 0; ks < 4; ks++) {
        const int jb = ks * 32 + lg * 8;
        bf16x8 av = *(const bf16x8*)&V_lds[(wv * 16 + li) * 136 + jb];
        #pragma unroll
        for (int itl = 0; itl < 8; itl++) {
            bf16x8 bp = *(const bf16x8*)&P_lds[(itl * 16 + li) * 136 + jb];
            ofr[itl] = __builtin_amdgcn_mfma_f32_16x16x32_bf16(av, bp, ofr[itl], 0, 0, 0);
        }
    }

    const float gamma = gptr[0];
    #pragma unroll
    for (int itl = 0; itl < 8; itl++) {
        const int i = itl * 16 + li;     // column index of this position
        float mWv = mW_s[i], sWv = sW_s[i];
        float mHv = mH_g[((size_t)b * 128 + i) * 128 + r];
        float sHv = sH_g[((size_t)b * 128 + i) * 128 + r];
        float m  = fmaxf(mHv, mWv);
        float wH = __expf(mHv - m);
        float wW = __expf(mWv - m);
        float invg = gamma / (sHv * wH + sWv * wW);
        #pragma unroll
        for (int rr = 0; rr < 4; rr++) {
            const int ch = wv * 16 + lg * 4 + rr;
            size_t o = (((size_t)b * 64 + ch) * 128 + r) * 128 + i;
            float Hv = bf2f(H_t[(((size_t)b * 128 + i) * 64 + ch) * 128 + r]);
            out[o] = (Hv * wH + ofr[itl][rr] * wW) * invg + x[o] + y[o];
        }
    }
}

// ---------------------------------------------------------------------------
extern "C" void kernel_launch(void* const* d_in, const int* in_sizes, int n_in,
                              void* d_out, int out_size, void* d_ws, size_t ws_size,
                              hipStream_t stream)
{
    const float* x     = (const float*)d_in[0];
    const float* y     = (const float*)d_in[1];
    const float* Wq    = (const float*)d_in[2];
    const float* bq    = (const float*)d_in[3];
    const float* Wk    = (const float*)d_in[4];
    const float* bk    = (const float*)d_in[5];
    const float* Wv    = (const float*)d_in[6];
    const float* bv    = (const float*)d_in[7];
    const float* gamma = (const float*)d_in[8];
    float* out = (float*)d_out;

    // Workspace: q 2MB | k 2MB | v 16MB | H_t 16MB (bf16) | mH 512KB | sH 512KB
    uint4* q_pm = (uint4*)d_ws;                         // 131072 uint4
    uint4* k_pm = q_pm + (size_t)BDIM * HW;             // 131072 uint4
    uint4* v_pm = k_pm + (size_t)BDIM * HW;             // 1048576 uint4
    ushort* H_t = (ushort*)(v_pm + (size_t)BDIM * HW * 8);   // 8388608 ushort
    float*  mH  = (float*)(H_t + (size_t)BDIM * 128 * 64 * 128);
    float*  sH  = mH + (size_t)BDIM * 128 * 128;

    qkv_kernel<<<dim3((BDIM * HW) / 256), dim3(256), 0, stream>>>(
        x, y, Wq, bq, Wk, bk, Wv, bv, q_pm, k_pm, v_pm);

    colattn_kernel<<<dim3(BDIM * WDIM), dim3(256), 0, stream>>>(
        q_pm, k_pm, v_pm, H_t, mH, sH);

    rowattn_kernel<<<dim3(BDIM * HDIM), dim3(256), 0, stream>>>(
        q_pm, k_pm, v_pm, H_t, mH, sH, x, y, gamma, out);
}

// Round 5
// 88.542 us; speedup vs baseline: 4.8258x; 1.4751x over previous
//
#include <hip/hip_runtime.h>
#include <hip/hip_bf16.h>

// Problem constants: B=8, C=64, C8=8, H=128, W=128
#define BDIM 8
#define CDIM 64
#define C8DIM 8
#define HDIM 128
#define WDIM 128
#define HW (HDIM * WDIM)   // 16384

typedef short bf16x8 __attribute__((ext_vector_type(8)));
typedef float f32x4 __attribute__((ext_vector_type(4)));

// ---------------- bf16 helpers ----------------
__device__ inline unsigned pk_bf16(float a, float b) {
    unsigned ua = (unsigned)__bfloat16_as_ushort(__float2bfloat16(a));
    unsigned ub = (unsigned)__bfloat16_as_ushort(__float2bfloat16(b));
    return ua | (ub << 16);
}
__device__ inline float bf2f(ushort u) { return __uint_as_float(((unsigned)u) << 16); }

// ---------------------------------------------------------------------------
// Kernel 1: fused QKV projection as MFMA GEMM.
//   D[o][p] = sum_c Wall[o][c] * X[c][p],  o in [0,80), c in [0,128), p tile=128
//   Wall rows: o<8 -> Wq (x chans), o<16 -> Wk (y chans), else Wv (x then y).
// One block per (b, 128-position tile). 4 waves; wave covers 32 positions
// (2 n-tiles), all 5 m-tiles, K=128 as 4 steps of 32.
// Weights: LDS bf16 [o][c] with XOR swizzle byte^=((o&7)<<4) (T2 pattern).
// X: NO LDS (zero reuse) -- B-fragments loaded per-lane from global fp32
// (8 dwords at channel stride) and converted to bf16 in-register.
// Outputs position-major bf16: q_pm[b][p][0..7], k_pm, v_pm[b][p][0..63].
// C/D layout: col = lane&15 (p), row = (lane>>4)*4 + reg (o) [HW-verified].
// ---------------------------------------------------------------------------
__global__ __launch_bounds__(256) void qkv_kernel(
    const float* __restrict__ x, const float* __restrict__ y,
    const float* __restrict__ Wq, const float* __restrict__ bq,
    const float* __restrict__ Wk, const float* __restrict__ bk,
    const float* __restrict__ Wv, const float* __restrict__ bv,
    uint4* __restrict__ q_pm, uint4* __restrict__ k_pm, uint4* __restrict__ v_pm)
{
    __shared__ ushort sW[80 * 128];   // [o][c] bf16, XOR-swizzled
    __shared__ float  sb[80];

    const int t = threadIdx.x;

    // ---- stage weights (one-time): 80x64 uint (=2 bf16) elements ----
    for (int i = t; i < 80 * 64; i += 256) {
        int o  = i >> 6;
        int cp = i & 63;
        int c  = cp * 2;
        float w0, w1;
        if (o < 8) {
            if (c < 64) { w0 = Wq[o * 64 + c]; w1 = Wq[o * 64 + c + 1]; }
            else        { w0 = 0.f; w1 = 0.f; }
        } else if (o < 16) {
            if (c >= 64) { w0 = Wk[(o - 8) * 64 + c - 64]; w1 = Wk[(o - 8) * 64 + c - 63]; }
            else         { w0 = 0.f; w1 = 0.f; }
        } else {
            w0 = Wv[(o - 16) * 128 + c];
            w1 = Wv[(o - 16) * 128 + c + 1];
        }
        // swizzled uint index: o*64 + (cp ^ ((o&7)<<2))
        ((unsigned*)sW)[o * 64 + (cp ^ ((o & 7) << 2))] = pk_bf16(w0, w1);
    }
    if (t < 80) {
        sb[t] = (t < 8) ? bq[t] : (t < 16) ? bk[t - 8] : bv[t - 16];
    }
    __syncthreads();

    const int blk = blockIdx.x;
    const int b   = blk & 7;
    const int p0  = (blk >> 3) << 7;    // position tile base

    const int wv = t >> 6, ln = t & 63, lg = ln >> 4, li = ln & 15;
    const int pcol0 = p0 + wv * 32 + li;   // this lane's nt2=0 position

    const float* xb = x + (size_t)b * CDIM * HW;
    const float* yb = y + (size_t)b * CDIM * HW;

    f32x4 acc[5][2];
    #pragma unroll
    for (int mt = 0; mt < 5; mt++)
        #pragma unroll
        for (int n = 0; n < 2; n++) acc[mt][n] = (f32x4){0.f, 0.f, 0.f, 0.f};

    #pragma unroll
    for (int kt = 0; kt < 4; kt++) {
        // B fragments: X[c = kt*32+lg*8+e][p], direct from global, cvt to bf16
        const float* srcbase = (kt < 2 ? xb : yb) + (size_t)((kt & 1) * 32 + lg * 8) * HW;
        bf16x8 bfr[2];
        #pragma unroll
        for (int n = 0; n < 2; n++) {
            const float* sp = srcbase + (size_t)(pcol0 + n * 16);
            float f[8];
            #pragma unroll
            for (int e = 0; e < 8; e++) f[e] = sp[(size_t)e * HW];
            uint4 u;
            u.x = pk_bf16(f[0], f[1]); u.y = pk_bf16(f[2], f[3]);
            u.z = pk_bf16(f[4], f[5]); u.w = pk_bf16(f[6], f[7]);
            bfr[n] = *(bf16x8*)&u;
        }
        // A fragments from swizzled LDS + MFMA
        #pragma unroll
        for (int mt = 0; mt < 5; mt++) {
            const int row  = mt * 16 + li;
            const int aidx = row * 128 + ((kt * 32 + lg * 8) ^ ((li & 7) << 3));
            bf16x8 a = *(const bf16x8*)&sW[aidx];
            #pragma unroll
            for (int n = 0; n < 2; n++)
                acc[mt][n] = __builtin_amdgcn_mfma_f32_16x16x32_bf16(a, bfr[n], acc[mt][n], 0, 0, 0);
        }
    }

    // ---- epilogue: +bias, pack 4 contiguous o, store to q/k/v (pos-major) ----
    #pragma unroll
    for (int mt = 0; mt < 5; mt++) {
        const int ob = mt * 16 + lg * 4;   // o base (multiple of 4)
        const float b0 = sb[ob + 0], b1 = sb[ob + 1], b2 = sb[ob + 2], b3 = sb[ob + 3];
        #pragma unroll
        for (int n = 0; n < 2; n++) {
            const size_t gp = (size_t)b * HW + (size_t)(pcol0 + n * 16);
            uint2 w;
            w.x = pk_bf16(acc[mt][n][0] + b0, acc[mt][n][1] + b1);
            w.y = pk_bf16(acc[mt][n][2] + b2, acc[mt][n][3] + b3);
            ushort* dst;
            if (ob < 8)       dst = (ushort*)q_pm + gp * 8 + ob;
            else if (ob < 16) dst = (ushort*)k_pm + gp * 8 + (ob - 8);
            else              dst = (ushort*)v_pm + gp * 64 + (ob - 16);
            *(uint2*)dst = w;
        }
    }
}

// ---------------------------------------------------------------------------
// Kernel 2 (column branch): one block per (b, c).  MFMA tile-GEMMs:
//   QK^T (swapped): D[j][i] = sum_ch K[j][ch] * Q[ch][i]   (K-dim = 8, padded)
//   per-row (i) softmax with diag mask (j == i -> -inf), unnormalized
//   PV: D2[ch][i] = sum_j V[ch][j] * P[j][i]
// Writes: H_t[b][c][ch][i] bf16 (unnormalized), mH[b][c][i], sH[b][c][i] f32.
// ---------------------------------------------------------------------------
__global__ __launch_bounds__(256, 2) void colattn_kernel(
    const uint4* __restrict__ q_pm, const uint4* __restrict__ k_pm,
    const uint4* __restrict__ v_pm,
    ushort* __restrict__ H_t, float* __restrict__ mH_g, float* __restrict__ sH_g)
{
    __shared__ ushort Q_lds[128 * 8];     // [i][ch]
    __shared__ ushort K_lds[128 * 8];     // [j][ch]
    __shared__ ushort V_lds[64 * 136];    // [ch][j], pad 8
    __shared__ ushort P_lds[128 * 136];   // [i][j], pad 8

    const int blk = blockIdx.x;
    const int b  = blk & 7;
    const int cc = blk >> 3;
    const int t  = threadIdx.x;

    if (t < 128) {
        *(uint4*)&Q_lds[t * 8] = q_pm[(size_t)b * HW + (size_t)t * 128 + cc];
    } else {
        int j = t - 128;
        *(uint4*)&K_lds[j * 8] = k_pm[(size_t)b * HW + (size_t)j * 128 + cc];
    }
    {
        int j = t & 127, h = t >> 7;
        const uint4* vp = v_pm + ((size_t)b * HW + (size_t)j * 128 + cc) * 8 + 4 * h;
        #pragma unroll
        for (int qd = 0; qd < 4; qd++) {
            uint4 vu = vp[qd];
            int ch0 = 32 * h + 8 * qd;
            V_lds[(ch0 + 0) * 136 + j] = (ushort)(vu.x & 0xffff);
            V_lds[(ch0 + 1) * 136 + j] = (ushort)(vu.x >> 16);
            V_lds[(ch0 + 2) * 136 + j] = (ushort)(vu.y & 0xffff);
            V_lds[(ch0 + 3) * 136 + j] = (ushort)(vu.y >> 16);
            V_lds[(ch0 + 4) * 136 + j] = (ushort)(vu.z & 0xffff);
            V_lds[(ch0 + 5) * 136 + j] = (ushort)(vu.z >> 16);
            V_lds[(ch0 + 6) * 136 + j] = (ushort)(vu.w & 0xffff);
            V_lds[(ch0 + 7) * 136 + j] = (ushort)(vu.w >> 16);
        }
    }
    __syncthreads();

    const int wv = t >> 6, ln = t & 63, lg = ln >> 4, li = ln & 15;
    const bf16x8 zf = {0, 0, 0, 0, 0, 0, 0, 0};

    // ---- QK^T ----
    bf16x8 afr[8], bfr[2];
    #pragma unroll
    for (int jt = 0; jt < 8; jt++)
        afr[jt] = (lg == 0) ? *(const bf16x8*)&K_lds[(jt * 16 + li) * 8] : zf;
    #pragma unroll
    for (int it2 = 0; it2 < 2; it2++)
        bfr[it2] = (lg == 0) ? *(const bf16x8*)&Q_lds[((2 * wv + it2) * 16 + li) * 8] : zf;

    f32x4 dfr[2][8];
    #pragma unroll
    for (int a = 0; a < 2; a++)
        #pragma unroll
        for (int jt = 0; jt < 8; jt++) dfr[a][jt] = (f32x4){0.f, 0.f, 0.f, 0.f};

    #pragma unroll
    for (int it2 = 0; it2 < 2; it2++)
        #pragma unroll
        for (int jt = 0; jt < 8; jt++)
            dfr[it2][jt] = __builtin_amdgcn_mfma_f32_16x16x32_bf16(
                afr[jt], bfr[it2], dfr[it2][jt], 0, 0, 0);

    // ---- softmax (unnormalized, diag masked) ----
    #pragma unroll
    for (int it2 = 0; it2 < 2; it2++) {
        const int i = (2 * wv + it2) * 16 + li;
        float m = -1e30f;
        #pragma unroll
        for (int jt = 0; jt < 8; jt++)
            #pragma unroll
            for (int rr = 0; rr < 4; rr++) {
                int j = jt * 16 + lg * 4 + rr;
                float e = dfr[it2][jt][rr];
                if (j == i) e = -1e30f;
                dfr[it2][jt][rr] = e;
                m = fmaxf(m, e);
            }
        m = fmaxf(m, __shfl_xor(m, 16));
        m = fmaxf(m, __shfl_xor(m, 32));
        float s = 0.f;
        #pragma unroll
        for (int jt = 0; jt < 8; jt++)
            #pragma unroll
            for (int rr = 0; rr < 4; rr++) {
                float p = __expf(dfr[it2][jt][rr] - m);
                dfr[it2][jt][rr] = p;
                s += p;
            }
        s += __shfl_xor(s, 16);
        s += __shfl_xor(s, 32);
        #pragma unroll
        for (int jt = 0; jt < 8; jt++) {
            uint2 w;
            w.x = pk_bf16(dfr[it2][jt][0], dfr[it2][jt][1]);
            w.y = pk_bf16(dfr[it2][jt][2], dfr[it2][jt][3]);
            *(uint2*)&P_lds[(size_t)i * 136 + jt * 16 + lg * 4] = w;
        }
        if (lg == 0) {
            mH_g[((size_t)b * 128 + cc) * 128 + i] = m;
            sH_g[((size_t)b * 128 + cc) * 128 + i] = s;
        }
    }
    __syncthreads();

    // ---- PV ----
    f32x4 ofr[8];
    #pragma unroll
    for (int itl = 0; itl < 8; itl++) ofr[itl] = (f32x4){0.f, 0.f, 0.f, 0.f};

    #pragma unroll
    for (int ks = 0; ks < 4; ks++) {
        const int jb = ks * 32 + lg * 8;
        bf16x8 av = *(const bf16x8*)&V_lds[(wv * 16 + li) * 136 + jb];
        #pragma unroll
        for (int itl = 0; itl < 8; itl++) {
            bf16x8 bp = *(const bf16x8*)&P_lds[(itl * 16 + li) * 136 + jb];
            ofr[itl] = __builtin_amdgcn_mfma_f32_16x16x32_bf16(av, bp, ofr[itl], 0, 0, 0);
        }
    }

    #pragma unroll
    for (int itl = 0; itl < 8; itl++) {
        const int i = itl * 16 + li;
        #pragma unroll
        for (int rr = 0; rr < 4; rr++) {
            const int ch = wv * 16 + lg * 4 + rr;
            H_t[(((size_t)b * 128 + cc) * 64 + ch) * 128 + i] =
                __bfloat16_as_ushort(__float2bfloat16(ofr[itl][rr]));
        }
    }
}

// ---------------------------------------------------------------------------
// Kernel 3 (row branch + merge): one block per (b, r).  Same GEMM structure
// (no diag mask); epilogue merges with the column branch (mH/sH/H_t) and adds
// the residual:  out = gamma*(H*wH + W*wW)/(sH*wH + sW*wW) + x + y.
// ---------------------------------------------------------------------------
__global__ __launch_bounds__(256, 2) void rowattn_kernel(
    const uint4* __restrict__ q_pm, const uint4* __restrict__ k_pm,
    const uint4* __restrict__ v_pm,
    const ushort* __restrict__ H_t, const float* __restrict__ mH_g,
    const float* __restrict__ sH_g,
    const float* __restrict__ x, const float* __restrict__ y,
    const float* __restrict__ gptr, float* __restrict__ out)
{
    __shared__ ushort Q_lds[128 * 8];     // [i][ch]  (i = column index)
    __shared__ ushort K_lds[128 * 8];     // [j][ch]
    __shared__ ushort V_lds[64 * 136];    // [ch][j]
    __shared__ ushort P_lds[128 * 136];   // [i][j]
    __shared__ float mW_s[128], sW_s[128];

    const int blk = blockIdx.x;
    const int b = blk & 7;
    const int r = blk >> 3;
    const int t = threadIdx.x;

    if (t < 128) {
        *(uint4*)&Q_lds[t * 8] = q_pm[(size_t)b * HW + (size_t)r * 128 + t];
    } else {
        int j = t - 128;
        *(uint4*)&K_lds[j * 8] = k_pm[(size_t)b * HW + (size_t)r * 128 + j];
    }
    {
        int j = t & 127, h = t >> 7;
        const uint4* vp = v_pm + ((size_t)b * HW + (size_t)r * 128 + j) * 8 + 4 * h;
        #pragma unroll
        for (int qd = 0; qd < 4; qd++) {
            uint4 vu = vp[qd];
            int ch0 = 32 * h + 8 * qd;
            V_lds[(ch0 + 0) * 136 + j] = (ushort)(vu.x & 0xffff);
            V_lds[(ch0 + 1) * 136 + j] = (ushort)(vu.x >> 16);
            V_lds[(ch0 + 2) * 136 + j] = (ushort)(vu.y & 0xffff);
            V_lds[(ch0 + 3) * 136 + j] = (ushort)(vu.y >> 16);
            V_lds[(ch0 + 4) * 136 + j] = (ushort)(vu.z & 0xffff);
            V_lds[(ch0 + 5) * 136 + j] = (ushort)(vu.z >> 16);
            V_lds[(ch0 + 6) * 136 + j] = (ushort)(vu.w & 0xffff);
            V_lds[(ch0 + 7) * 136 + j] = (ushort)(vu.w >> 16);
        }
    }
    __syncthreads();

    const int wv = t >> 6, ln = t & 63, lg = ln >> 4, li = ln & 15;
    const bf16x8 zf = {0, 0, 0, 0, 0, 0, 0, 0};

    bf16x8 afr[8], bfr[2];
    #pragma unroll
    for (int jt = 0; jt < 8; jt++)
        afr[jt] = (lg == 0) ? *(const bf16x8*)&K_lds[(jt * 16 + li) * 8] : zf;
    #pragma unroll
    for (int it2 = 0; it2 < 2; it2++)
        bfr[it2] = (lg == 0) ? *(const bf16x8*)&Q_lds[((2 * wv + it2) * 16 + li) * 8] : zf;

    f32x4 dfr[2][8];
    #pragma unroll
    for (int a = 0; a < 2; a++)
        #pragma unroll
        for (int jt = 0; jt < 8; jt++) dfr[a][jt] = (f32x4){0.f, 0.f, 0.f, 0.f};

    #pragma unroll
    for (int it2 = 0; it2 < 2; it2++)
        #pragma unroll
        for (int jt = 0; jt < 8; jt++)
            dfr[it2][jt] = __builtin_amdgcn_mfma_f32_16x16x32_bf16(
                afr[jt], bfr[it2], dfr[it2][jt], 0, 0, 0);

    #pragma unroll
    for (int it2 = 0; it2 < 2; it2++) {
        const int i = (2 * wv + it2) * 16 + li;
        float m = -1e30f;
        #pragma unroll
        for (int jt = 0; jt < 8; jt++)
            #pragma unroll
            for (int rr = 0; rr < 4; rr++)
                m = fmaxf(m, dfr[it2][jt][rr]);
        m = fmaxf(m, __shfl_xor(m, 16));
        m = fmaxf(m, __shfl_xor(m, 32));
        float s = 0.f;
        #pragma unroll
        for (int jt = 0; jt < 8; jt++)
            #pragma unroll
            for (int rr = 0; rr < 4; rr++) {
                float p = __expf(dfr[it2][jt][rr] - m);
                dfr[it2][jt][rr] = p;
                s += p;
            }
        s += __shfl_xor(s, 16);
        s += __shfl_xor(s, 32);
        #pragma unroll
        for (int jt = 0; jt < 8; jt++) {
            uint2 w;
            w.x = pk_bf16(dfr[it2][jt][0], dfr[it2][jt][1]);
            w.y = pk_bf16(dfr[it2][jt][2], dfr[it2][jt][3]);
            *(uint2*)&P_lds[(size_t)i * 136 + jt * 16 + lg * 4] = w;
        }
        if (lg == 0) {
            mW_s[i] = m;
            sW_s[i] = s;
        }
    }
    __syncthreads();

    f32x4 ofr[8];
    #pragma unroll
    for (int itl = 0; itl < 8; itl++) ofr[itl] = (f32x4){0.f, 0.f, 0.f, 0.f};

    #pragma unroll
    for (int ks = 0; ks < 4; ks++) {
        const int jb = ks * 32 + lg * 8;
        bf16x8 av = *(const bf16x8*)&V_lds[(wv * 16 + li) * 136 + jb];
        #pragma unroll
        for (int itl = 0; itl < 8; itl++) {
            bf16x8 bp = *(const bf16x8*)&P_lds[(itl * 16 + li) * 136 + jb];
            ofr[itl] = __builtin_amdgcn_mfma_f32_16x16x32_bf16(av, bp, ofr[itl], 0, 0, 0);
        }
    }

    const float gamma = gptr[0];
    #pragma unroll
    for (int itl = 0; itl < 8; itl++) {
        const int i = itl * 16 + li;     // column index of this position
        float mWv = mW_s[i], sWv = sW_s[i];
        float mHv = mH_g[((size_t)b * 128 + i) * 128 + r];
        float sHv = sH_g[((size_t)b * 128 + i) * 128 + r];
        float m  = fmaxf(mHv, mWv);
        float wH = __expf(mHv - m);
        float wW = __expf(mWv - m);
        float invg = gamma / (sHv * wH + sWv * wW);
        #pragma unroll
        for (int rr = 0; rr < 4; rr++) {
            const int ch = wv * 16 + lg * 4 + rr;
            size_t o = (((size_t)b * 64 + ch) * 128 + r) * 128 + i;
            float Hv = bf2f(H_t[(((size_t)b * 128 + i) * 64 + ch) * 128 + r]);
            out[o] = (Hv * wH + ofr[itl][rr] * wW) * invg + x[o] + y[o];
        }
    }
}

// ---------------------------------------------------------------------------
extern "C" void kernel_launch(void* const* d_in, const int* in_sizes, int n_in,
                              void* d_out, int out_size, void* d_ws, size_t ws_size,
                              hipStream_t stream)
{
    const float* x     = (const float*)d_in[0];
    const float* y     = (const float*)d_in[1];
    const float* Wq    = (const float*)d_in[2];
    const float* bq    = (const float*)d_in[3];
    const float* Wk    = (const float*)d_in[4];
    const float* bk    = (const float*)d_in[5];
    const float* Wv    = (const float*)d_in[6];
    const float* bv    = (const float*)d_in[7];
    const float* gamma = (const float*)d_in[8];
    float* out = (float*)d_out;

    // Workspace: q 2MB | k 2MB | v 16MB | H_t 16MB (bf16) | mH 512KB | sH 512KB
    uint4* q_pm = (uint4*)d_ws;                         // 131072 uint4
    uint4* k_pm = q_pm + (size_t)BDIM * HW;             // 131072 uint4
    uint4* v_pm = k_pm + (size_t)BDIM * HW;             // 1048576 uint4
    ushort* H_t = (ushort*)(v_pm + (size_t)BDIM * HW * 8);   // 8388608 ushort
    float*  mH  = (float*)(H_t + (size_t)BDIM * 128 * 64 * 128);
    float*  sH  = mH + (size_t)BDIM * 128 * 128;

    qkv_kernel<<<dim3(BDIM * HW / 128), dim3(256), 0, stream>>>(
        x, y, Wq, bq, Wk, bk, Wv, bv, q_pm, k_pm, v_pm);

    colattn_kernel<<<dim3(BDIM * WDIM), dim3(256), 0, stream>>>(
        q_pm, k_pm, v_pm, H_t, mH, sH);

    rowattn_kernel<<<dim3(BDIM * HDIM), dim3(256), 0, stream>>>(
        q_pm, k_pm, v_pm, H_t, mH, sH, x, y, gamma, out);
}

// Round 6
// 70.770 us; speedup vs baseline: 6.0376x; 1.2511x over previous
//
#include <hip/hip_runtime.h>
#include <hip/hip_bf16.h>

// Problem constants: B=8, C=64, C8=8, H=128, W=128
#define BDIM 8
#define CDIM 64
#define C8DIM 8
#define HDIM 128
#define WDIM 128
#define HW (HDIM * WDIM)   // 16384

typedef short bf16x8 __attribute__((ext_vector_type(8)));
typedef float f32x4 __attribute__((ext_vector_type(4)));

// ---------------- bf16 helpers ----------------
__device__ inline unsigned pk_bf16(float a, float b) {
    unsigned ua = (unsigned)__bfloat16_as_ushort(__float2bfloat16(a));
    unsigned ub = (unsigned)__bfloat16_as_ushort(__float2bfloat16(b));
    return ua | (ub << 16);
}
__device__ inline void cvt2(unsigned u, float& lo, float& hi) {
    lo = __uint_as_float(u << 16);
    hi = __uint_as_float(u & 0xffff0000u);
}
__device__ inline float bf2f(ushort u) { return __uint_as_float(((unsigned)u) << 16); }

// ---------------------------------------------------------------------------
// Kernel 1: fused QKV projection as MFMA GEMM (+ optional bf16 x+y residual).
//   D[o][p] = sum_c Wall[o][c] * X[c][p],  o in [0,80), c in [0,128)
// One block per (b, 128-position tile). 4 waves; wave covers 32 positions
// (2 n-tiles), all 5 m-tiles, K=128 as 2 pairs of (x-ch 32, y-ch 32).
// Weights: LDS bf16 [o][c], XOR swizzle ushort-idx ^= ((o&7)<<3) -- wait, the
// swizzle below is on the c index within a row keyed by li of the READER; the
// writer mirrors it. X: no LDS (zero reuse); B-fragments direct from global.
// xy_pm (optional): bf16 x+y, layout [b][p][ch 0..63].
// C/D layout: col = lane&15 (p), row = (lane>>4)*4 + reg (o) [HW-verified].
// ---------------------------------------------------------------------------
__global__ __launch_bounds__(256) void qkv_kernel(
    const float* __restrict__ x, const float* __restrict__ y,
    const float* __restrict__ Wq, const float* __restrict__ bq,
    const float* __restrict__ Wk, const float* __restrict__ bk,
    const float* __restrict__ Wv, const float* __restrict__ bv,
    uint4* __restrict__ q_pm, uint4* __restrict__ k_pm, uint4* __restrict__ v_pm,
    ushort* __restrict__ xy_pm)
{
    __shared__ ushort sW[80 * 128];   // [o][c] bf16, XOR-swizzled
    __shared__ float  sb[80];

    const int t = threadIdx.x;

    // ---- stage weights (one-time): 80x64 uint (=2 bf16) elements ----
    for (int i = t; i < 80 * 64; i += 256) {
        int o  = i >> 6;
        int cp = i & 63;
        int c  = cp * 2;
        float w0, w1;
        if (o < 8) {
            if (c < 64) { w0 = Wq[o * 64 + c]; w1 = Wq[o * 64 + c + 1]; }
            else        { w0 = 0.f; w1 = 0.f; }
        } else if (o < 16) {
            if (c >= 64) { w0 = Wk[(o - 8) * 64 + c - 64]; w1 = Wk[(o - 8) * 64 + c - 63]; }
            else         { w0 = 0.f; w1 = 0.f; }
        } else {
            w0 = Wv[(o - 16) * 128 + c];
            w1 = Wv[(o - 16) * 128 + c + 1];
        }
        ((unsigned*)sW)[o * 64 + (cp ^ ((o & 7) << 2))] = pk_bf16(w0, w1);
    }
    if (t < 80) {
        sb[t] = (t < 8) ? bq[t] : (t < 16) ? bk[t - 8] : bv[t - 16];
    }
    __syncthreads();

    const int blk = blockIdx.x;
    const int b   = blk & 7;
    const int p0  = (blk >> 3) << 7;    // position tile base

    const int wv = t >> 6, ln = t & 63, lg = ln >> 4, li = ln & 15;
    const int pcol0 = p0 + wv * 32 + li;   // this lane's n=0 position

    const float* xb = x + (size_t)b * CDIM * HW;
    const float* yb = y + (size_t)b * CDIM * HW;

    f32x4 acc[5][2];
    #pragma unroll
    for (int mt = 0; mt < 5; mt++)
        #pragma unroll
        for (int n = 0; n < 2; n++) acc[mt][n] = (f32x4){0.f, 0.f, 0.f, 0.f};

    #pragma unroll
    for (int pair = 0; pair < 2; pair++) {
        const int chb = pair * 32 + lg * 8;          // x/y channel base
        const float* xp = xb + (size_t)chb * HW;
        const float* yp = yb + (size_t)chb * HW;
        bf16x8 bx[2], by[2];
        #pragma unroll
        for (int n = 0; n < 2; n++) {
            const size_t poff = (size_t)(pcol0 + n * 16);
            float fx[8], fy[8];
            #pragma unroll
            for (int e = 0; e < 8; e++) {
                fx[e] = xp[(size_t)e * HW + poff];
                fy[e] = yp[(size_t)e * HW + poff];
            }
            uint4 ux, uy;
            ux.x = pk_bf16(fx[0], fx[1]); ux.y = pk_bf16(fx[2], fx[3]);
            ux.z = pk_bf16(fx[4], fx[5]); ux.w = pk_bf16(fx[6], fx[7]);
            uy.x = pk_bf16(fy[0], fy[1]); uy.y = pk_bf16(fy[2], fy[3]);
            uy.z = pk_bf16(fy[4], fy[5]); uy.w = pk_bf16(fy[6], fy[7]);
            bx[n] = *(bf16x8*)&ux;
            by[n] = *(bf16x8*)&uy;
            if (xy_pm) {
                uint4 s;
                s.x = pk_bf16(fx[0] + fy[0], fx[1] + fy[1]);
                s.y = pk_bf16(fx[2] + fy[2], fx[3] + fy[3]);
                s.z = pk_bf16(fx[4] + fy[4], fx[5] + fy[5]);
                s.w = pk_bf16(fx[6] + fy[6], fx[7] + fy[7]);
                *(uint4*)&xy_pm[((size_t)b * HW + poff) * 64 + chb] = s;
            }
        }
        // MFMA: x weights (c0 = pair*32+lg*8), y weights (c0 = 64+pair*32+lg*8)
        #pragma unroll
        for (int mt = 0; mt < 5; mt++) {
            const int row = mt * 16 + li;
            const int sw  = ((li & 7) << 3);
            bf16x8 ax = *(const bf16x8*)&sW[row * 128 + ((pair * 32 + lg * 8) ^ sw)];
            bf16x8 ay = *(const bf16x8*)&sW[row * 128 + (((2 + pair) * 32 + lg * 8) ^ sw)];
            #pragma unroll
            for (int n = 0; n < 2; n++) {
                acc[mt][n] = __builtin_amdgcn_mfma_f32_16x16x32_bf16(ax, bx[n], acc[mt][n], 0, 0, 0);
                acc[mt][n] = __builtin_amdgcn_mfma_f32_16x16x32_bf16(ay, by[n], acc[mt][n], 0, 0, 0);
            }
        }
    }

    // ---- epilogue: +bias, pack 4 contiguous o, store to q/k/v (pos-major) ----
    #pragma unroll
    for (int mt = 0; mt < 5; mt++) {
        const int ob = mt * 16 + lg * 4;   // o base (multiple of 4)
        const float b0 = sb[ob + 0], b1 = sb[ob + 1], b2 = sb[ob + 2], b3 = sb[ob + 3];
        #pragma unroll
        for (int n = 0; n < 2; n++) {
            const size_t gp = (size_t)b * HW + (size_t)(pcol0 + n * 16);
            uint2 w;
            w.x = pk_bf16(acc[mt][n][0] + b0, acc[mt][n][1] + b1);
            w.y = pk_bf16(acc[mt][n][2] + b2, acc[mt][n][3] + b3);
            ushort* dst;
            if (ob < 8)       dst = (ushort*)q_pm + gp * 8 + ob;
            else if (ob < 16) dst = (ushort*)k_pm + gp * 8 + (ob - 8);
            else              dst = (ushort*)v_pm + gp * 64 + (ob - 16);
            *(uint2*)dst = w;
        }
    }
}

// ---------------------------------------------------------------------------
// Kernel 2 (column branch): one block per (b, c).  MFMA tile-GEMMs:
//   QK^T (swapped): D[j][i] = sum_ch K[j][ch] * Q[ch][i]
//   per-row (i) softmax with diag mask, unnormalized
//   PV: D2[ch][i] = sum_j V[ch][j] * P[j][i]
// Writes: H_t[b][row=i][col=cc][ch] bf16 (uint2 stores), mH[b][cc][i], sH.
// ---------------------------------------------------------------------------
__global__ __launch_bounds__(256, 2) void colattn_kernel(
    const uint4* __restrict__ q_pm, const uint4* __restrict__ k_pm,
    const uint4* __restrict__ v_pm,
    ushort* __restrict__ H_t, float* __restrict__ mH_g, float* __restrict__ sH_g)
{
    __shared__ ushort Q_lds[128 * 8];     // [i][ch]
    __shared__ ushort K_lds[128 * 8];     // [j][ch]
    __shared__ ushort V_lds[64 * 136];    // [ch][j], pad 8
    __shared__ ushort P_lds[128 * 136];   // [i][j], pad 8

    const int blk = blockIdx.x;
    const int b  = blk & 7;
    const int cc = blk >> 3;
    const int t  = threadIdx.x;

    if (t < 128) {
        *(uint4*)&Q_lds[t * 8] = q_pm[(size_t)b * HW + (size_t)t * 128 + cc];
    } else {
        int j = t - 128;
        *(uint4*)&K_lds[j * 8] = k_pm[(size_t)b * HW + (size_t)j * 128 + cc];
    }
    {
        int j = t & 127, h = t >> 7;
        const uint4* vp = v_pm + ((size_t)b * HW + (size_t)j * 128 + cc) * 8 + 4 * h;
        #pragma unroll
        for (int qd = 0; qd < 4; qd++) {
            uint4 vu = vp[qd];
            int ch0 = 32 * h + 8 * qd;
            V_lds[(ch0 + 0) * 136 + j] = (ushort)(vu.x & 0xffff);
            V_lds[(ch0 + 1) * 136 + j] = (ushort)(vu.x >> 16);
            V_lds[(ch0 + 2) * 136 + j] = (ushort)(vu.y & 0xffff);
            V_lds[(ch0 + 3) * 136 + j] = (ushort)(vu.y >> 16);
            V_lds[(ch0 + 4) * 136 + j] = (ushort)(vu.z & 0xffff);
            V_lds[(ch0 + 5) * 136 + j] = (ushort)(vu.z >> 16);
            V_lds[(ch0 + 6) * 136 + j] = (ushort)(vu.w & 0xffff);
            V_lds[(ch0 + 7) * 136 + j] = (ushort)(vu.w >> 16);
        }
    }
    __syncthreads();

    const int wv = t >> 6, ln = t & 63, lg = ln >> 4, li = ln & 15;
    const bf16x8 zf = {0, 0, 0, 0, 0, 0, 0, 0};

    // ---- QK^T ----
    bf16x8 afr[8], bfr[2];
    #pragma unroll
    for (int jt = 0; jt < 8; jt++)
        afr[jt] = (lg == 0) ? *(const bf16x8*)&K_lds[(jt * 16 + li) * 8] : zf;
    #pragma unroll
    for (int it2 = 0; it2 < 2; it2++)
        bfr[it2] = (lg == 0) ? *(const bf16x8*)&Q_lds[((2 * wv + it2) * 16 + li) * 8] : zf;

    f32x4 dfr[2][8];
    #pragma unroll
    for (int a = 0; a < 2; a++)
        #pragma unroll
        for (int jt = 0; jt < 8; jt++) dfr[a][jt] = (f32x4){0.f, 0.f, 0.f, 0.f};

    #pragma unroll
    for (int it2 = 0; it2 < 2; it2++)
        #pragma unroll
        for (int jt = 0; jt < 8; jt++)
            dfr[it2][jt] = __builtin_amdgcn_mfma_f32_16x16x32_bf16(
                afr[jt], bfr[it2], dfr[it2][jt], 0, 0, 0);

    // ---- softmax (unnormalized, diag masked) ----
    #pragma unroll
    for (int it2 = 0; it2 < 2; it2++) {
        const int i = (2 * wv + it2) * 16 + li;
        float m = -1e30f;
        #pragma unroll
        for (int jt = 0; jt < 8; jt++)
            #pragma unroll
            for (int rr = 0; rr < 4; rr++) {
                int j = jt * 16 + lg * 4 + rr;
                float e = dfr[it2][jt][rr];
                if (j == i) e = -1e30f;
                dfr[it2][jt][rr] = e;
                m = fmaxf(m, e);
            }
        m = fmaxf(m, __shfl_xor(m, 16));
        m = fmaxf(m, __shfl_xor(m, 32));
        float s = 0.f;
        #pragma unroll
        for (int jt = 0; jt < 8; jt++)
            #pragma unroll
            for (int rr = 0; rr < 4; rr++) {
                float p = __expf(dfr[it2][jt][rr] - m);
                dfr[it2][jt][rr] = p;
                s += p;
            }
        s += __shfl_xor(s, 16);
        s += __shfl_xor(s, 32);
        #pragma unroll
        for (int jt = 0; jt < 8; jt++) {
            uint2 w;
            w.x = pk_bf16(dfr[it2][jt][0], dfr[it2][jt][1]);
            w.y = pk_bf16(dfr[it2][jt][2], dfr[it2][jt][3]);
            *(uint2*)&P_lds[(size_t)i * 136 + jt * 16 + lg * 4] = w;
        }
        if (lg == 0) {
            mH_g[((size_t)b * 128 + cc) * 128 + i] = m;
            sH_g[((size_t)b * 128 + cc) * 128 + i] = s;
        }
    }
    __syncthreads();

    // ---- PV ----
    f32x4 ofr[8];
    #pragma unroll
    for (int itl = 0; itl < 8; itl++) ofr[itl] = (f32x4){0.f, 0.f, 0.f, 0.f};

    #pragma unroll
    for (int ks = 0; ks < 4; ks++) {
        const int jb = ks * 32 + lg * 8;
        bf16x8 av = *(const bf16x8*)&V_lds[(wv * 16 + li) * 136 + jb];
        #pragma unroll
        for (int itl = 0; itl < 8; itl++) {
            bf16x8 bp = *(const bf16x8*)&P_lds[(itl * 16 + li) * 136 + jb];
            ofr[itl] = __builtin_amdgcn_mfma_f32_16x16x32_bf16(av, bp, ofr[itl], 0, 0, 0);
        }
    }

    // ---- store H_t[b][row=i][col=cc][ch], 8B per (itl) ----
    #pragma unroll
    for (int itl = 0; itl < 8; itl++) {
        const int i = itl * 16 + li;
        uint2 w;
        w.x = pk_bf16(ofr[itl][0], ofr[itl][1]);
        w.y = pk_bf16(ofr[itl][2], ofr[itl][3]);
        *(uint2*)&H_t[(((size_t)b * 128 + i) * 128 + cc) * 64 + wv * 16 + lg * 4] = w;
    }
}

// ---------------------------------------------------------------------------
// Kernel 3 (row branch + merge): one block per (b, r).  Same GEMM structure
// (no diag mask); epilogue merges with the column branch (mH/sH/H_t) and adds
// the residual:  out = (H*wH + W*wW) * gamma/(sH*wH + sW*wW) + (x + y).
// USE_XY: residual from bf16 xy_pm (written by qkv) instead of fp32 x,y.
// ---------------------------------------------------------------------------
template<int USE_XY>
__global__ __launch_bounds__(256, 2) void rowattn_kernel(
    const uint4* __restrict__ q_pm, const uint4* __restrict__ k_pm,
    const uint4* __restrict__ v_pm,
    const ushort* __restrict__ H_t, const float* __restrict__ mH_g,
    const float* __restrict__ sH_g,
    const float* __restrict__ x, const float* __restrict__ y,
    const ushort* __restrict__ xy_pm,
    const float* __restrict__ gptr, float* __restrict__ out)
{
    __shared__ ushort Q_lds[128 * 8];     // [i][ch]  (i = column index)
    __shared__ ushort K_lds[128 * 8];     // [j][ch]
    __shared__ ushort V_lds[64 * 136];    // [ch][j]
    __shared__ ushort P_lds[128 * 136];   // [i][j]
    __shared__ float mW_s[128], sW_s[128];

    const int blk = blockIdx.x;
    const int b = blk & 7;
    const int r = blk >> 3;
    const int t = threadIdx.x;

    if (t < 128) {
        *(uint4*)&Q_lds[t * 8] = q_pm[(size_t)b * HW + (size_t)r * 128 + t];
    } else {
        int j = t - 128;
        *(uint4*)&K_lds[j * 8] = k_pm[(size_t)b * HW + (size_t)r * 128 + j];
    }
    {
        int j = t & 127, h = t >> 7;
        const uint4* vp = v_pm + ((size_t)b * HW + (size_t)r * 128 + j) * 8 + 4 * h;
        #pragma unroll
        for (int qd = 0; qd < 4; qd++) {
            uint4 vu = vp[qd];
            int ch0 = 32 * h + 8 * qd;
            V_lds[(ch0 + 0) * 136 + j] = (ushort)(vu.x & 0xffff);
            V_lds[(ch0 + 1) * 136 + j] = (ushort)(vu.x >> 16);
            V_lds[(ch0 + 2) * 136 + j] = (ushort)(vu.y & 0xffff);
            V_lds[(ch0 + 3) * 136 + j] = (ushort)(vu.y >> 16);
            V_lds[(ch0 + 4) * 136 + j] = (ushort)(vu.z & 0xffff);
            V_lds[(ch0 + 5) * 136 + j] = (ushort)(vu.z >> 16);
            V_lds[(ch0 + 6) * 136 + j] = (ushort)(vu.w & 0xffff);
            V_lds[(ch0 + 7) * 136 + j] = (ushort)(vu.w >> 16);
        }
    }
    __syncthreads();

    const int wv = t >> 6, ln = t & 63, lg = ln >> 4, li = ln & 15;
    const bf16x8 zf = {0, 0, 0, 0, 0, 0, 0, 0};

    bf16x8 afr[8], bfr[2];
    #pragma unroll
    for (int jt = 0; jt < 8; jt++)
        afr[jt] = (lg == 0) ? *(const bf16x8*)&K_lds[(jt * 16 + li) * 8] : zf;
    #pragma unroll
    for (int it2 = 0; it2 < 2; it2++)
        bfr[it2] = (lg == 0) ? *(const bf16x8*)&Q_lds[((2 * wv + it2) * 16 + li) * 8] : zf;

    f32x4 dfr[2][8];
    #pragma unroll
    for (int a = 0; a < 2; a++)
        #pragma unroll
        for (int jt = 0; jt < 8; jt++) dfr[a][jt] = (f32x4){0.f, 0.f, 0.f, 0.f};

    #pragma unroll
    for (int it2 = 0; it2 < 2; it2++)
        #pragma unroll
        for (int jt = 0; jt < 8; jt++)
            dfr[it2][jt] = __builtin_amdgcn_mfma_f32_16x16x32_bf16(
                afr[jt], bfr[it2], dfr[it2][jt], 0, 0, 0);

    #pragma unroll
    for (int it2 = 0; it2 < 2; it2++) {
        const int i = (2 * wv + it2) * 16 + li;
        float m = -1e30f;
        #pragma unroll
        for (int jt = 0; jt < 8; jt++)
            #pragma unroll
            for (int rr = 0; rr < 4; rr++)
                m = fmaxf(m, dfr[it2][jt][rr]);
        m = fmaxf(m, __shfl_xor(m, 16));
        m = fmaxf(m, __shfl_xor(m, 32));
        float s = 0.f;
        #pragma unroll
        for (int jt = 0; jt < 8; jt++)
            #pragma unroll
            for (int rr = 0; rr < 4; rr++) {
                float p = __expf(dfr[it2][jt][rr] - m);
                dfr[it2][jt][rr] = p;
                s += p;
            }
        s += __shfl_xor(s, 16);
        s += __shfl_xor(s, 32);
        #pragma unroll
        for (int jt = 0; jt < 8; jt++) {
            uint2 w;
            w.x = pk_bf16(dfr[it2][jt][0], dfr[it2][jt][1]);
            w.y = pk_bf16(dfr[it2][jt][2], dfr[it2][jt][3]);
            *(uint2*)&P_lds[(size_t)i * 136 + jt * 16 + lg * 4] = w;
        }
        if (lg == 0) {
            mW_s[i] = m;
            sW_s[i] = s;
        }
    }
    __syncthreads();

    f32x4 ofr[8];
    #pragma unroll
    for (int itl = 0; itl < 8; itl++) ofr[itl] = (f32x4){0.f, 0.f, 0.f, 0.f};

    #pragma unroll
    for (int ks = 0; ks < 4; ks++) {
        const int jb = ks * 32 + lg * 8;
        bf16x8 av = *(const bf16x8*)&V_lds[(wv * 16 + li) * 136 + jb];
        #pragma unroll
        for (int itl = 0; itl < 8; itl++) {
            bf16x8 bp = *(const bf16x8*)&P_lds[(itl * 16 + li) * 136 + jb];
            ofr[itl] = __builtin_amdgcn_mfma_f32_16x16x32_bf16(av, bp, ofr[itl], 0, 0, 0);
        }
    }

    const float gamma = gptr[0];
    #pragma unroll
    for (int itl = 0; itl < 8; itl++) {
        const int i = itl * 16 + li;     // column index of this position
        float mWv = mW_s[i], sWv = sW_s[i];
        float mHv = mH_g[((size_t)b * 128 + i) * 128 + r];
        float sHv = sH_g[((size_t)b * 128 + i) * 128 + r];
        float m  = fmaxf(mHv, mWv);
        float wH = __expf(mHv - m);
        float wW = __expf(mWv - m);
        float invg = gamma / (sHv * wH + sWv * wW);

        // coalesced-footprint H read: [b][r][i][ch], 8B per lane per itl
        uint2 hw = *(const uint2*)&H_t[(((size_t)b * 128 + r) * 128 + i) * 64 + wv * 16 + lg * 4];
        float h[4];
        cvt2(hw.x, h[0], h[1]);
        cvt2(hw.y, h[2], h[3]);

        float resid[4];
        if (USE_XY) {
            uint2 xu = *(const uint2*)&xy_pm[((size_t)b * HW + (size_t)r * 128 + i) * 64 + wv * 16 + lg * 4];
            cvt2(xu.x, resid[0], resid[1]);
            cvt2(xu.y, resid[2], resid[3]);
        }

        #pragma unroll
        for (int rr = 0; rr < 4; rr++) {
            const int ch = wv * 16 + lg * 4 + rr;
            size_t o = (((size_t)b * 64 + ch) * 128 + r) * 128 + i;
            float res = USE_XY ? resid[rr] : (x[o] + y[o]);
            out[o] = (h[rr] * wH + ofr[itl][rr] * wW) * invg + res;
        }
    }
}

// ---------------------------------------------------------------------------
extern "C" void kernel_launch(void* const* d_in, const int* in_sizes, int n_in,
                              void* d_out, int out_size, void* d_ws, size_t ws_size,
                              hipStream_t stream)
{
    const float* x     = (const float*)d_in[0];
    const float* y     = (const float*)d_in[1];
    const float* Wq    = (const float*)d_in[2];
    const float* bq    = (const float*)d_in[3];
    const float* Wk    = (const float*)d_in[4];
    const float* bk    = (const float*)d_in[5];
    const float* Wv    = (const float*)d_in[6];
    const float* bv    = (const float*)d_in[7];
    const float* gamma = (const float*)d_in[8];
    float* out = (float*)d_out;

    // Workspace: q 2MB | k 2MB | v 16MB | H_t 16MB | mH .5MB | sH .5MB | xy 16MB
    uint4*  q_pm = (uint4*)d_ws;                        // 131072 uint4
    uint4*  k_pm = q_pm + (size_t)BDIM * HW;            // 131072 uint4
    uint4*  v_pm = k_pm + (size_t)BDIM * HW;            // 1048576 uint4
    ushort* H_t  = (ushort*)(v_pm + (size_t)BDIM * HW * 8);      // 8388608 us
    float*  mH   = (float*)(H_t + (size_t)BDIM * HW * 64);
    float*  sH   = mH + (size_t)BDIM * HW;
    ushort* xy   = (ushort*)(sH + (size_t)BDIM * HW);            // 8388608 us
    size_t need  = (size_t)((char*)(xy + (size_t)BDIM * HW * 64) - (char*)d_ws);
    const bool use_xy = ws_size >= need;

    qkv_kernel<<<dim3(BDIM * HW / 128), dim3(256), 0, stream>>>(
        x, y, Wq, bq, Wk, bk, Wv, bv, q_pm, k_pm, v_pm,
        use_xy ? xy : (ushort*)nullptr);

    colattn_kernel<<<dim3(BDIM * WDIM), dim3(256), 0, stream>>>(
        q_pm, k_pm, v_pm, H_t, mH, sH);

    if (use_xy) {
        rowattn_kernel<1><<<dim3(BDIM * HDIM), dim3(256), 0, stream>>>(
            q_pm, k_pm, v_pm, H_t, mH, sH, x, y, xy, gamma, out);
    } else {
        rowattn_kernel<0><<<dim3(BDIM * HDIM), dim3(256), 0, stream>>>(
            q_pm, k_pm, v_pm, H_t, mH, sH, x, y, xy, gamma, out);
    }
}